// Round 14
// baseline (69.016 us; speedup 1.0000x reference)
//
#include <hip/hip_runtime.h>
#include <math.h>
#include <stdint.h>

#define NS    16
#define HWSZ  409600
#define NF4   102400      // float4s per sample
#define NBIN  128
#define SLW   (NBIN + 8)  // slice: count hist + 8 scalars (cp,cn,p1,p2,n1,n2,s3,s4)
#define CAP   4096
#define BCAP  512         // per-block LDS candidate staging
#define SBPS  80          // scan blocks per sample (5 pipelined iters of 256 f4) -> 1280 blocks = 5/CU exact
#define GBPS  100         // gather blocks per sample
#define PADI  32          // ints per sample for padded atomic counter (128 B)

typedef unsigned long long u64;
typedef float f32x4 __attribute__((ext_vector_type(4)));

__device__ __forceinline__ unsigned fkey(float f) {
    unsigned u = __float_as_uint(f);
    if (u == 0x80000000u) u = 0u;                 // canonicalize -0
    return (u & 0x80000000u) ? ~u : (u | 0x80000000u);
}

// bce1: BCE on p; bce2: BCE on sigmoid(50(p-t)); both with 1e-7 clipping
__device__ __forceinline__ void bce_pair(float pv, float tv, bool tc, float& o1, float& o2) {
    float pc = fminf(fmaxf(pv, 1e-7f), 1.0f - 1e-7f);
    float a = tc ? pc : 1.0f - pc;
    o1 = -__logf(a);
    float x = 50.0f * (pv - tv);
    float y = tc ? -x : x;
    float t2 = __expf(-fabsf(y));
    float sp = __logf(1.0f + t2);
    sp = (y > 0.0f) ? y + sp : sp;
    o2 = fminf(sp, 16.118095651f);
}

__device__ __forceinline__ int pbin(float p) {
    int b = (int)(p * (float)NBIN);
    return min(max(b, 0), NBIN - 1);
}

// Wave-parallel descending k-th-largest bin search over a histogram.
__device__ __forceinline__ bool wave_find(const int* __restrict__ h, int nbins, int k,
                                          int* bin_out, int* rank_out) {
    const int lane = threadIdx.x & 63;
    const int CH = nbins >> 6;
    const int topStart = nbins - 1 - lane * CH;
    int s = 0;
    for (int b = 0; b < CH; ++b) s += h[topStart - b];
    int incl = s;
    for (int off = 1; off < 64; off <<= 1) {
        int v = __shfl_up(incl, off, 64);
        if (lane >= off) incl += v;
    }
    int before = incl - s;
    if (before < k && k <= incl) {
        int c = before;
        for (int b = 0; b < CH; ++b) {
            int hb = h[topStart - b];
            c += hb;
            if (c >= k) { *bin_out = topStart - b; *rank_out = k - (c - hb); return true; }
        }
    }
    return false;
}

#define GLOAD(dst, addr) \
    asm volatile("global_load_dwordx4 %0, %1, off" : "=v"(dst) : "v"(addr))
#define LOADSET(Sp, St, Sg, Sq, Sm, Sd, idx) do { \
    GLOAD(Sp, P + (idx));  GLOAD(St, Th + (idx)); GLOAD(Sg, G + (idx)); \
    GLOAD(Sq, Gt + (idx)); GLOAD(Sm, T + (idx)); GLOAD(Sd, D + (idx)); } while (0)
#define WAITSET(Sp, St, Sg, Sq, Sm, Sd, N) \
    asm volatile("s_waitcnt vmcnt(" #N ")" \
                 : "+v"(Sp), "+v"(St), "+v"(Sg), "+v"(Sq), "+v"(Sm), "+v"(Sd))

// ---------------- fat pass: 3-deep pipelined streaming, 5 iters/block -------
__global__ void k_scan1(const float* __restrict__ outputs, const float* __restrict__ labels,
                        const float* __restrict__ tmask, const float* __restrict__ gd,
                        float* __restrict__ part) {
    __shared__ int lc[NBIN];
    __shared__ float rf[4][6];
    __shared__ int ri[4][2];
    const int t = threadIdx.x, n = blockIdx.y, lane = t & 63, wid = t >> 6;
    if (t < NBIN) lc[t] = 0;
    __syncthreads();
    const f32x4* P  = (const f32x4*)(outputs + (size_t)n * 2 * HWSZ);
    const f32x4* Th = P + NF4;
    const f32x4* G  = (const f32x4*)(labels + (size_t)n * 2 * HWSZ);
    const f32x4* Gt = G + NF4;
    const f32x4* T  = (const f32x4*)(tmask + (size_t)n * HWSZ);
    const f32x4* D  = (const f32x4*)(gd + (size_t)n * HWSZ);
    const int i0 = blockIdx.x * 1280 + t;         // 5 iterations, stride 256
    float s3 = 0.f, s4 = 0.f, p1 = 0.f, p2 = 0.f, n1 = 0.f, n2 = 0.f;
    int cp = 0, cn = 0;
    auto proc = [&](const f32x4& p, const f32x4& th, const f32x4& g, const f32x4& q,
                    const f32x4& m, const f32x4& d) {
#pragma unroll
        for (int e = 0; e < 4; ++e) {
            float pv = p[e], tv = th[e], gv = g[e], qv = q[e], mv = m[e], dv = d[e];
            s3 += fabsf(tv - qv) * dv;
            s4 += dv;
            bool msk = mv > 0.5f, tc = gv > 0.5f;
            if (msk) {
                float o1, o2; bce_pair(pv, tv, tc, o1, o2);
                if (tc) { p1 += o1; p2 += o2; cp++; }
                else    { n1 += o1; n2 += o2; cn++; atomicAdd(&lc[pbin(pv)], 1); }
            }
        }
    };
    f32x4 ap, at, ag, aq, am, ad, bp, bt, bg, bq, bm, bd, cq, ct, cg, cqq, cm, cd;
    // 3-deep rotation over 5 iters: never drains to 0 mid-stream
    LOADSET(ap, at, ag, aq, am, ad, i0);              // A = iter 0
    LOADSET(bp, bt, bg, bq, bm, bd, i0 + 256);        // B = iter 1
    LOADSET(cq, ct, cg, cqq, cm, cd, i0 + 512);       // C = iter 2
    WAITSET(ap, at, ag, aq, am, ad, 12);
    proc(ap, at, ag, aq, am, ad);
    LOADSET(ap, at, ag, aq, am, ad, i0 + 768);        // A = iter 3
    WAITSET(bp, bt, bg, bq, bm, bd, 12);
    proc(bp, bt, bg, bq, bm, bd);
    LOADSET(bp, bt, bg, bq, bm, bd, i0 + 1024);       // B = iter 4
    WAITSET(cq, ct, cg, cqq, cm, cd, 12);
    proc(cq, ct, cg, cqq, cm, cd);
    WAITSET(ap, at, ag, aq, am, ad, 6);
    proc(ap, at, ag, aq, am, ad);
    WAITSET(bp, bt, bg, bq, bm, bd, 0);
    proc(bp, bt, bg, bq, bm, bd);
    for (int off = 32; off; off >>= 1) {
        p1 += __shfl_down(p1, off, 64);
        p2 += __shfl_down(p2, off, 64);
        n1 += __shfl_down(n1, off, 64);
        n2 += __shfl_down(n2, off, 64);
        s3 += __shfl_down(s3, off, 64);
        s4 += __shfl_down(s4, off, 64);
        cp += __shfl_down(cp, off, 64);
        cn += __shfl_down(cn, off, 64);
    }
    if (!lane) {
        rf[wid][0] = p1; rf[wid][1] = p2; rf[wid][2] = n1;
        rf[wid][3] = n2; rf[wid][4] = s3; rf[wid][5] = s4;
        ri[wid][0] = cp; ri[wid][1] = cn;
    }
    __syncthreads();
    float* slice = part + (size_t)(n * SBPS + blockIdx.x) * SLW;
    int* slice_i = (int*)slice;
    if (t < NBIN) slice_i[t] = lc[t];
    if (!t) {
        slice_i[NBIN + 0] = ri[0][0] + ri[1][0] + ri[2][0] + ri[3][0];
        slice_i[NBIN + 1] = ri[0][1] + ri[1][1] + ri[2][1] + ri[3][1];
#pragma unroll
        for (int i = 0; i < 6; ++i)
            slice[NBIN + 2 + i] = rf[0][i] + rf[1][i] + rf[2][i] + rf[3][i];
    }
}

// ---------------- per-sample: reduce partials + select + zero counters ------
// modes: 0 = threshold in boundary bin; 1 = pos only; 2 = all masked; 3 = all neg+pos
__global__ void k_sel1(const float* __restrict__ part,
                       int* __restrict__ mode, int* __restrict__ b1o, int* __restrict__ k1o,
                       int* __restrict__ poss,
                       double* __restrict__ psum, double* __restrict__ abD, int* __restrict__ abc,
                       double* __restrict__ s3s, double* __restrict__ s4s,
                       int* __restrict__ cand_cnt, unsigned* __restrict__ gdone,
                       unsigned* __restrict__ fdone) {
    __shared__ int lc[NBIN];
    __shared__ double sdr[4][6];
    __shared__ int sir[4][2];
    __shared__ int ric[4];
    __shared__ int sb1, sk1, s_md, s_k;
    const int n = blockIdx.x, t = threadIdx.x, lane = t & 63, wid = t >> 6;
    // zero per-call mutable state for the next kernel (launch-ordered, poison-safe)
    if (t < PADI) cand_cnt[n * PADI + t] = 0;
    if (!t) { gdone[n] = 0u; if (!n) *fdone = 0u; }
    const float* base = part + (size_t)n * SBPS * SLW;
    double v[6] = {0, 0, 0, 0, 0, 0};
    int cp = 0, cn = 0;
    if (t < SBPS) {
        const float* sl = base + (size_t)t * SLW;
        const int* sli = (const int*)sl;
        cp = sli[NBIN + 0]; cn = sli[NBIN + 1];
#pragma unroll
        for (int i = 0; i < 6; ++i) v[i] = (double)sl[NBIN + 2 + i];
    }
    for (int off = 32; off; off >>= 1) {
#pragma unroll
        for (int i = 0; i < 6; ++i) v[i] += __shfl_down(v[i], off, 64);
        cp += __shfl_down(cp, off, 64);
        cn += __shfl_down(cn, off, 64);
    }
    if (!lane) {
#pragma unroll
        for (int i = 0; i < 6; ++i) sdr[wid][i] = v[i];
        sir[wid][0] = cp; sir[wid][1] = cn;
    }
    __syncthreads();
    if (!t) {
        int pos = sir[0][0] + sir[1][0] + sir[2][0] + sir[3][0];
        int neg = sir[0][1] + sir[1][1] + sir[2][1] + sir[3][1];
        double c[6];
#pragma unroll
        for (int i = 0; i < 6; ++i) c[i] = sdr[0][i] + sdr[1][i] + sdr[2][i] + sdr[3][i];
        int k = pos * 3; if (k > neg) k = neg;
        int md = (pos == 0) ? 2 : ((k == 0) ? 1 : ((k == neg) ? 3 : 0));
        mode[n] = md;
        poss[n] = pos;
        psum[n * 2 + 0] = c[0];     // pos bce1 sum
        psum[n * 2 + 1] = c[1];     // pos bce2 sum
        s3s[n] = c[4];
        s4s[n] = c[5];
        if (md == 1)      { abD[n * 16] = 0.0;  abD[n * 16 + 1] = 0.0;  abc[n] = 0; }
        else if (md != 0) { abD[n * 16] = c[2]; abD[n * 16 + 1] = c[3]; abc[n] = neg; }
        else              { abD[n * 16] = 0.0;  abD[n * 16 + 1] = 0.0; }  // gather fills
        s_md = md; s_k = k;
    }
    __syncthreads();
    if (s_md != 0) return;
    // ---- count-histogram reduction (2 thread-groups × 40 slices)
    if (t < NBIN) lc[t] = 0;
    __syncthreads();
    {
        const int bin = t & (NBIN - 1);
        const int j0 = (t < NBIN) ? 0 : SBPS / 2;
        const int j1 = (t < NBIN) ? SBPS / 2 : SBPS;
        int c = 0;
        for (int j = j0; j < j1; ++j) c += ((const int*)(base + (size_t)j * SLW))[bin];
        atomicAdd(&lc[bin], c);
    }
    __syncthreads();
    if (t < 64) { int b, r; if (wave_find(lc, NBIN, s_k, &b, &r)) { sb1 = b; sk1 = r; } }
    __syncthreads();
    const int B = sb1;
    if (!t) { b1o[n] = sb1; k1o[n] = sk1; }
    int ac = (t < NBIN && t > B) ? lc[t] : 0;
    for (int off = 32; off; off >>= 1) ac += __shfl_down(ac, off, 64);
    if (!lane) ric[wid] = ac;
    __syncthreads();
    if (!t) abc[n] = ric[0] + ric[1] + ric[2] + ric[3];
}

// ---------------- fused gather + finalize + global reduction ----------------
__global__ void k_gf(const float* __restrict__ outputs, const float* __restrict__ labels,
                     const float* __restrict__ tmask,
                     const int* __restrict__ mode, const int* __restrict__ b1a,
                     const int* __restrict__ k1a, const int* __restrict__ poss,
                     int* __restrict__ cand_cnt, unsigned* __restrict__ ck,
                     float* __restrict__ cv1, float* __restrict__ cv2,
                     double* __restrict__ abD,
                     const double* __restrict__ psum, const int* __restrict__ abc,
                     double* __restrict__ res,
                     const double* __restrict__ s3s, const double* __restrict__ s4s,
                     unsigned* __restrict__ gdone, unsigned* __restrict__ fdone,
                     float* __restrict__ out) {
    __shared__ int lcnt, lbase, s_last;
    __shared__ unsigned lsk[BCAP];
    __shared__ float lv1[BCAP], lv2[BCAP];
    __shared__ double rdd[4][2];
    __shared__ int h[2048];
    __shared__ int sbh, srh, sbm, srm, sbl;
    __shared__ double rd[4][2];
    __shared__ int ri[4];
    const int n = blockIdx.y, t = threadIdx.x, lane = t & 63, wid = t >> 6;
    const int md = mode[n];
    // ------------- gather phase (mode 0 only) -------------
    if (md == 0) {
        const int b1n = b1a[n];
        if (!t) lcnt = 0;
        __syncthreads();
        const float* bp = outputs + (size_t)n * 2 * HWSZ;
        const float4* P  = (const float4*)bp;
        const float4* Th = P + NF4;
        const float4* G  = (const float4*)(labels + (size_t)n * 2 * HWSZ);
        const float4* T  = (const float4*)(tmask + (size_t)n * HWSZ);
        const int stride = GBPS * 256;
        float a1 = 0.f, a2 = 0.f;
        for (int i4 = blockIdx.x * 256 + t; i4 < NF4; i4 += stride) {
            float4 p = P[i4], th = Th[i4], g = G[i4], m = T[i4];
            const float* pp = (const float*)&p;  const float* tt = (const float*)&th;
            const float* gg = (const float*)&g;  const float* mm = (const float*)&m;
#pragma unroll
            for (int e = 0; e < 4; ++e) {
                bool neg = (gg[e] <= 0.5f) && (mm[e] > 0.5f);
                int bin = pbin(pp[e]);
                if (neg && bin >= b1n) {
                    float o1, o2; bce_pair(pp[e], tt[e], false, o1, o2);
                    if (bin > b1n) { a1 += o1; a2 += o2; }
                    else {
                        int idx = atomicAdd(&lcnt, 1);
                        if (idx < BCAP) { lsk[idx] = fkey(pp[e]); lv1[idx] = o1; lv2[idx] = o2; }
                        else {
                            int gi = atomicAdd(&cand_cnt[n * PADI], 1);   // rare overflow
                            if (gi < CAP) { ck[n * CAP + gi] = fkey(pp[e]); cv1[n * CAP + gi] = o1; cv2[n * CAP + gi] = o2; }
                        }
                    }
                }
            }
        }
        double v0 = a1, v1 = a2;
        for (int off = 32; off; off >>= 1) {
            v0 += __shfl_down(v0, off, 64);
            v1 += __shfl_down(v1, off, 64);
        }
        if (!lane) { rdd[wid][0] = v0; rdd[wid][1] = v1; }
        __syncthreads();
        if (!t) {
            double sA = rdd[0][0] + rdd[1][0] + rdd[2][0] + rdd[3][0];
            double sB = rdd[0][1] + rdd[1][1] + rdd[2][1] + rdd[3][1];
            if (sA != 0.0) atomicAdd(&abD[n * 16], sA);
            if (sB != 0.0) atomicAdd(&abD[n * 16 + 1], sB);
        }
        __syncthreads();
        const int cnt = min(lcnt, BCAP);
        if (!t && cnt) lbase = atomicAdd(&cand_cnt[n * PADI], cnt);
        __syncthreads();
        if (cnt) {
            const int bb = lbase;
            for (int i = t; i < cnt; i += 256) {
                int gi = bb + i;
                if (gi < CAP) { ck[n * CAP + gi] = lsk[i]; cv1[n * CAP + gi] = lv1[i]; cv2[n * CAP + gi] = lv2[i]; }
            }
        }
    }
    // ------------- per-sample completion gate -------------
    __syncthreads();
    if (!t) { __threadfence(); s_last = (atomicAdd(&gdone[n], 1u) == GBPS - 1) ? 1 : 0; }
    __syncthreads();
    if (!s_last) return;
    __threadfence();                               // acquire all gather publishes
    // ------------- finalize phase (last block of sample n) -------------
    double f1r = 0.0, f2r = 0.0; int fcr = 0;
    if (md == 0) {
        const int k1 = k1a[n];
        const int cc = cand_cnt[n * PADI];
        const unsigned* ckn = ck + n * CAP;
        const float* c1n = cv1 + n * CAP;
        const float* c2n = cv2 + n * CAP;
        float f1 = 0.f, f2 = 0.f; int fc = 0;
        if (cc <= CAP) {
            for (int i = t; i < 2048; i += 256) h[i] = 0;
            __syncthreads();
            for (int i = t; i < cc; i += 256) atomicAdd(&h[ckn[i] >> 21], 1);
            __syncthreads();
            if (t < 64) { int b, r; if (wave_find(h, 2048, k1, &b, &r)) { sbh = b; srh = r; } }
            __syncthreads();
            const unsigned bh = (unsigned)sbh; const int r2 = srh;
            for (int i = t; i < 2048; i += 256) h[i] = 0;
            __syncthreads();
            for (int i = t; i < cc; i += 256)
                if ((ckn[i] >> 21) == bh) atomicAdd(&h[(ckn[i] >> 10) & 0x7FFu], 1);
            __syncthreads();
            if (t < 64) { int b, r; if (wave_find(h, 2048, r2, &b, &r)) { sbm = b; srm = r; } }
            __syncthreads();
            const unsigned bm = (unsigned)sbm; const int r3 = srm;
            for (int i = t; i < 1024; i += 256) h[i] = 0;
            __syncthreads();
            for (int i = t; i < cc; i += 256)
                if ((ckn[i] >> 10) == ((bh << 11) | bm)) atomicAdd(&h[ckn[i] & 0x3FFu], 1);
            __syncthreads();
            if (t < 64) { int b, r; if (wave_find(h, 1024, r3, &b, &r)) sbl = b; }
            __syncthreads();
            const unsigned thr_key = (bh << 21) | (bm << 10) | (unsigned)sbl;
            for (int i = t; i < cc; i += 256)
                if (ckn[i] >= thr_key) { f1 += c1n[i]; f2 += c2n[i]; fc++; }
        } else {
            // slow path: rescan boundary bin from global (general insurance)
            const int b1n = b1a[n];
            const float* Pp = outputs + (size_t)n * 2 * HWSZ;
            const float* Thp = Pp + HWSZ;
            const float* Gp = labels + (size_t)n * 2 * HWSZ;
            const float* Tp = tmask + (size_t)n * HWSZ;
            for (int i = t; i < 2048; i += 256) h[i] = 0;
            __syncthreads();
            for (int i = t; i < HWSZ; i += 256) {
                float pv = Pp[i];
                if (Gp[i] <= 0.5f && Tp[i] > 0.5f && pbin(pv) == b1n)
                    atomicAdd(&h[fkey(pv) >> 21], 1);
            }
            __syncthreads();
            if (t < 64) { int b, r; if (wave_find(h, 2048, k1, &b, &r)) { sbh = b; srh = r; } }
            __syncthreads();
            const unsigned bh = (unsigned)sbh; const int r2 = srh;
            for (int i = t; i < 2048; i += 256) h[i] = 0;
            __syncthreads();
            for (int i = t; i < HWSZ; i += 256) {
                float pv = Pp[i]; unsigned key = fkey(pv);
                if (Gp[i] <= 0.5f && Tp[i] > 0.5f && pbin(pv) == b1n && (key >> 21) == bh)
                    atomicAdd(&h[(key >> 10) & 0x7FFu], 1);
            }
            __syncthreads();
            if (t < 64) { int b, r; if (wave_find(h, 2048, r2, &b, &r)) { sbm = b; srm = r; } }
            __syncthreads();
            const unsigned bm = (unsigned)sbm; const int r3 = srm;
            for (int i = t; i < 1024; i += 256) h[i] = 0;
            __syncthreads();
            for (int i = t; i < HWSZ; i += 256) {
                float pv = Pp[i]; unsigned key = fkey(pv);
                if (Gp[i] <= 0.5f && Tp[i] > 0.5f && pbin(pv) == b1n && (key >> 10) == ((bh << 11) | bm))
                    atomicAdd(&h[key & 0x3FFu], 1);
            }
            __syncthreads();
            if (t < 64) { int b, r; if (wave_find(h, 1024, r3, &b, &r)) sbl = b; }
            __syncthreads();
            const unsigned thr_key = (bh << 21) | (bm << 10) | (unsigned)sbl;
            for (int i = t; i < HWSZ; i += 256) {
                float pv = Pp[i];
                if (Gp[i] <= 0.5f && Tp[i] > 0.5f && pbin(pv) == b1n && fkey(pv) >= thr_key) {
                    float b1v, b2v; bce_pair(pv, Thp[i], false, b1v, b2v);
                    f1 += b1v; f2 += b2v; fc++;
                }
            }
        }
        double v0 = f1, v1 = f2;
        for (int off = 32; off; off >>= 1) {
            v0 += __shfl_down(v0, off, 64);
            v1 += __shfl_down(v1, off, 64);
            fc += __shfl_down(fc, off, 64);
        }
        if (!lane) { rd[wid][0] = v0; rd[wid][1] = v1; ri[wid] = fc; }
        __syncthreads();
        if (!t) {
            f1r = rd[0][0] + rd[1][0] + rd[2][0] + rd[3][0];
            f2r = rd[0][1] + rd[1][1] + rd[2][1] + rd[3][1];
            fcr = ri[0] + ri[1] + ri[2] + ri[3];
        }
    }
    if (!t) {
        res[n * 3 + 0] = psum[n * 2 + 0] + abD[n * 16] + f1r;
        res[n * 3 + 1] = psum[n * 2 + 1] + abD[n * 16 + 1] + f2r;
        res[n * 3 + 2] = (double)poss[n] + (double)abc[n] + (double)fcr;
        __threadfence();                           // publish res before signaling
        unsigned v = atomicAdd(fdone, 1u);
        if (v == NS - 1) {                         // global last: emit outputs
            __threadfence();                       // acquire all res stores
            double A = 0.0, Bb = 0.0, C = 0.0, S3 = 0.0, S4 = 0.0;
            for (int m = 0; m < NS; ++m) {
                A += res[m * 3 + 0]; Bb += res[m * 3 + 1]; C += res[m * 3 + 2];
                S3 += s3s[m]; S4 += s4s[m];
            }
            double lp = (C > 0.0) ? A / C : 0.0;
            double lb = (C > 0.0) ? Bb / C : 0.0;
            double lt = S3 / (S4 + 1e-6);
            out[0] = (float)(lp + lb + 10.0 * lt);
            out[1] = (float)lp;
            out[2] = (float)lb;
            out[3] = (float)lt;
        }
    }
}

extern "C" void kernel_launch(void* const* d_in, const int* in_sizes, int n_in,
                              void* d_out, int out_size, void* d_ws, size_t ws_size,
                              hipStream_t stream) {
    const float* outputs = (const float*)d_in[0];
    const float* labels  = (const float*)d_in[1];
    const float* tmask   = (const float*)d_in[2];
    const float* gd      = (const float*)d_in[3];
    float* out = (float*)d_out;

    char* ws = (char*)d_ws;
    double* s3s   = (double*)ws;                 // NS
    double* s4s   = s3s + NS;                    // NS
    double* psum  = s4s + NS;                    // NS*2
    double* abD   = psum + NS * 2;               // NS*16 (padded: [n*16]=ab1,[n*16+1]=ab2)
    double* res   = abD + NS * 16;               // NS*3
    int* abc      = (int*)(res + NS * 3);        // NS
    int* mode     = abc + NS;                    // NS
    int* b1       = mode + NS;                   // NS
    int* k1       = b1 + NS;                     // NS
    int* poss     = k1 + NS;                     // NS
    unsigned* gdone = (unsigned*)(poss + NS);    // NS
    unsigned* fdone = gdone + NS;                // 1 (+pad to 8)
    int* cand_cnt = (int*)(fdone + 8);           // NS*PADI (padded counters)
    float* part   = (float*)(cand_cnt + NS * PADI);  // NS*SBPS*SLW (fully written)
    unsigned* ck  = (unsigned*)(part + (size_t)NS * SBPS * SLW);  // NS*CAP
    float* cv1    = (float*)(ck + NS * CAP);
    float* cv2    = cv1 + NS * CAP;
    (void)cv2; (void)ws_size; (void)in_sizes; (void)n_in; (void)out_size;

    // No memset: k_sel1 zeroes cand_cnt/gdone/fdone before k_gf consumes them,
    // and every other workspace word is written before it is read.
    k_scan1<<<dim3(SBPS, NS), 256, 0, stream>>>(outputs, labels, tmask, gd, part);
    k_sel1<<<NS, 256, 0, stream>>>(part, mode, b1, k1, poss, psum, abD, abc, s3s, s4s,
                                   cand_cnt, gdone, fdone);
    k_gf<<<dim3(GBPS, NS), 256, 0, stream>>>(outputs, labels, tmask, mode, b1, k1, poss,
                                             cand_cnt, ck, cv1, cv2, abD, psum, abc, res,
                                             s3s, s4s, gdone, fdone, out);
}

// Round 15
// 39.033 us; speedup vs baseline: 1.7681x; 1.7681x over previous
//
#include <hip/hip_runtime.h>
#include <math.h>
#include <stdint.h>

#define NS    16
#define HWSZ  409600
#define NF4   102400      // float4s per sample
#define NBIN  128
#define SLW   (NBIN + 8)  // slice: count hist + 8 scalars (cp,cn,p1,p2,n1,n2,s3,s4)
#define CAP   4096
#define BCAP  512         // per-block LDS candidate staging
#define SBPS  100         // scan blocks per sample (4 pipelined iters of 256 f4)
#define GBPS  100         // gather blocks per sample
#define PADI  32          // ints per sample for padded atomic counter (128 B)

typedef unsigned long long u64;
typedef float f32x4 __attribute__((ext_vector_type(4)));

__device__ __forceinline__ unsigned fkey(float f) {
    unsigned u = __float_as_uint(f);
    if (u == 0x80000000u) u = 0u;                 // canonicalize -0
    return (u & 0x80000000u) ? ~u : (u | 0x80000000u);
}

// bce1: BCE on p; bce2: BCE on sigmoid(50(p-t)); both with 1e-7 clipping
__device__ __forceinline__ void bce_pair(float pv, float tv, bool tc, float& o1, float& o2) {
    float pc = fminf(fmaxf(pv, 1e-7f), 1.0f - 1e-7f);
    float a = tc ? pc : 1.0f - pc;
    o1 = -__logf(a);
    float x = 50.0f * (pv - tv);
    float y = tc ? -x : x;
    float t2 = __expf(-fabsf(y));
    float sp = __logf(1.0f + t2);
    sp = (y > 0.0f) ? y + sp : sp;
    o2 = fminf(sp, 16.118095651f);
}

__device__ __forceinline__ int pbin(float p) {
    int b = (int)(p * (float)NBIN);
    return min(max(b, 0), NBIN - 1);
}

// Wave-parallel descending k-th-largest bin search over a histogram.
__device__ __forceinline__ bool wave_find(const int* __restrict__ h, int nbins, int k,
                                          int* bin_out, int* rank_out) {
    const int lane = threadIdx.x & 63;
    const int CH = nbins >> 6;
    const int topStart = nbins - 1 - lane * CH;
    int s = 0;
    for (int b = 0; b < CH; ++b) s += h[topStart - b];
    int incl = s;
    for (int off = 1; off < 64; off <<= 1) {
        int v = __shfl_up(incl, off, 64);
        if (lane >= off) incl += v;
    }
    int before = incl - s;
    if (before < k && k <= incl) {
        int c = before;
        for (int b = 0; b < CH; ++b) {
            int hb = h[topStart - b];
            c += hb;
            if (c >= k) { *bin_out = topStart - b; *rank_out = k - (c - hb); return true; }
        }
    }
    return false;
}

#define GLOAD(dst, addr) \
    asm volatile("global_load_dwordx4 %0, %1, off" : "=v"(dst) : "v"(addr))
#define LOADSET(Sp, St, Sg, Sq, Sm, Sd, idx) do { \
    GLOAD(Sp, P + (idx));  GLOAD(St, Th + (idx)); GLOAD(Sg, G + (idx)); \
    GLOAD(Sq, Gt + (idx)); GLOAD(Sm, T + (idx)); GLOAD(Sd, D + (idx)); } while (0)
#define WAITSET(Sp, St, Sg, Sq, Sm, Sd, N) \
    asm volatile("s_waitcnt vmcnt(" #N ")" \
                 : "+v"(Sp), "+v"(St), "+v"(Sg), "+v"(Sq), "+v"(Sm), "+v"(Sd))

// ---------------- fat pass: 3-deep pipelined streaming ----------------------
__global__ void k_scan1(const float* __restrict__ outputs, const float* __restrict__ labels,
                        const float* __restrict__ tmask, const float* __restrict__ gd,
                        float* __restrict__ part) {
    __shared__ int lc[NBIN];
    __shared__ float rf[4][6];
    __shared__ int ri[4][2];
    const int t = threadIdx.x, n = blockIdx.y, lane = t & 63, wid = t >> 6;
    if (t < NBIN) lc[t] = 0;
    __syncthreads();
    const f32x4* P  = (const f32x4*)(outputs + (size_t)n * 2 * HWSZ);
    const f32x4* Th = P + NF4;
    const f32x4* G  = (const f32x4*)(labels + (size_t)n * 2 * HWSZ);
    const f32x4* Gt = G + NF4;
    const f32x4* T  = (const f32x4*)(tmask + (size_t)n * HWSZ);
    const f32x4* D  = (const f32x4*)(gd + (size_t)n * HWSZ);
    const int i0 = blockIdx.x * 1024 + t;         // 4 iterations, stride 256
    float s3 = 0.f, s4 = 0.f, p1 = 0.f, p2 = 0.f, n1 = 0.f, n2 = 0.f;
    int cp = 0, cn = 0;
    auto proc = [&](const f32x4& p, const f32x4& th, const f32x4& g, const f32x4& q,
                    const f32x4& m, const f32x4& d) {
#pragma unroll
        for (int e = 0; e < 4; ++e) {
            float pv = p[e], tv = th[e], gv = g[e], qv = q[e], mv = m[e], dv = d[e];
            s3 += fabsf(tv - qv) * dv;
            s4 += dv;
            bool msk = mv > 0.5f, tc = gv > 0.5f;
            if (msk) {
                float o1, o2; bce_pair(pv, tv, tc, o1, o2);
                if (tc) { p1 += o1; p2 += o2; cp++; }
                else    { n1 += o1; n2 += o2; cn++; atomicAdd(&lc[pbin(pv)], 1); }
            }
        }
    };
    f32x4 ap, at, ag, aq, am, ad, bp, bt, bg, bq, bm, bd, cq, ct, cg, cqq, cm, cd;
    // 3-deep: 18 loads in flight; counted waits keep >=6 outstanding mid-stream
    LOADSET(ap, at, ag, aq, am, ad, i0);              // set A = iter 0
    LOADSET(bp, bt, bg, bq, bm, bd, i0 + 256);        // set B = iter 1
    LOADSET(cq, ct, cg, cqq, cm, cd, i0 + 512);       // set C = iter 2
    WAITSET(ap, at, ag, aq, am, ad, 12);
    proc(ap, at, ag, aq, am, ad);
    LOADSET(ap, at, ag, aq, am, ad, i0 + 768);        // set A = iter 3
    WAITSET(bp, bt, bg, bq, bm, bd, 12);
    proc(bp, bt, bg, bq, bm, bd);
    WAITSET(cq, ct, cg, cqq, cm, cd, 6);
    proc(cq, ct, cg, cqq, cm, cd);
    WAITSET(ap, at, ag, aq, am, ad, 0);
    proc(ap, at, ag, aq, am, ad);
    for (int off = 32; off; off >>= 1) {
        p1 += __shfl_down(p1, off, 64);
        p2 += __shfl_down(p2, off, 64);
        n1 += __shfl_down(n1, off, 64);
        n2 += __shfl_down(n2, off, 64);
        s3 += __shfl_down(s3, off, 64);
        s4 += __shfl_down(s4, off, 64);
        cp += __shfl_down(cp, off, 64);
        cn += __shfl_down(cn, off, 64);
    }
    if (!lane) {
        rf[wid][0] = p1; rf[wid][1] = p2; rf[wid][2] = n1;
        rf[wid][3] = n2; rf[wid][4] = s3; rf[wid][5] = s4;
        ri[wid][0] = cp; ri[wid][1] = cn;
    }
    __syncthreads();
    float* slice = part + (size_t)(n * SBPS + blockIdx.x) * SLW;
    int* slice_i = (int*)slice;
    if (t < NBIN) slice_i[t] = lc[t];
    if (!t) {
        slice_i[NBIN + 0] = ri[0][0] + ri[1][0] + ri[2][0] + ri[3][0];
        slice_i[NBIN + 1] = ri[0][1] + ri[1][1] + ri[2][1] + ri[3][1];
#pragma unroll
        for (int i = 0; i < 6; ++i)
            slice[NBIN + 2 + i] = rf[0][i] + rf[1][i] + rf[2][i] + rf[3][i];
    }
}

// ---------------- per-sample: reduce partials + select + suffix count -------
// modes: 0 = threshold in boundary bin; 1 = pos only; 2 = all masked; 3 = all neg+pos
__global__ void k_sel1(const float* __restrict__ part,
                       int* __restrict__ mode, int* __restrict__ b1o, int* __restrict__ k1o,
                       int* __restrict__ poss,
                       double* __restrict__ psum, double* __restrict__ abD, int* __restrict__ abc,
                       double* __restrict__ s3s, double* __restrict__ s4s,
                       int* __restrict__ cand_cnt, unsigned* __restrict__ done) {
    __shared__ int lc[NBIN];
    __shared__ double sdr[4][6];
    __shared__ int sir[4][2];
    __shared__ int ric[4];
    __shared__ int sb1, sk1, s_md, s_k;
    const int n = blockIdx.x, t = threadIdx.x, lane = t & 63, wid = t >> 6;
    // zero the per-call mutable state (replaces host-side memset)
    if (t < PADI) cand_cnt[n * PADI + t] = 0;
    if (!n && !t) *done = 0u;
    const float* base = part + (size_t)n * SBPS * SLW;
    double v[6] = {0, 0, 0, 0, 0, 0};
    int cp = 0, cn = 0;
    if (t < SBPS) {
        const float* sl = base + (size_t)t * SLW;
        const int* sli = (const int*)sl;
        cp = sli[NBIN + 0]; cn = sli[NBIN + 1];
#pragma unroll
        for (int i = 0; i < 6; ++i) v[i] = (double)sl[NBIN + 2 + i];
    }
    for (int off = 32; off; off >>= 1) {
#pragma unroll
        for (int i = 0; i < 6; ++i) v[i] += __shfl_down(v[i], off, 64);
        cp += __shfl_down(cp, off, 64);
        cn += __shfl_down(cn, off, 64);
    }
    if (!lane) {
#pragma unroll
        for (int i = 0; i < 6; ++i) sdr[wid][i] = v[i];
        sir[wid][0] = cp; sir[wid][1] = cn;
    }
    __syncthreads();
    if (!t) {
        int pos = sir[0][0] + sir[1][0] + sir[2][0] + sir[3][0];
        int neg = sir[0][1] + sir[1][1] + sir[2][1] + sir[3][1];
        double c[6];
#pragma unroll
        for (int i = 0; i < 6; ++i) c[i] = sdr[0][i] + sdr[1][i] + sdr[2][i] + sdr[3][i];
        int k = pos * 3; if (k > neg) k = neg;
        int md = (pos == 0) ? 2 : ((k == 0) ? 1 : ((k == neg) ? 3 : 0));
        mode[n] = md;
        poss[n] = pos;
        psum[n * 2 + 0] = c[0];     // pos bce1 sum
        psum[n * 2 + 1] = c[1];     // pos bce2 sum
        s3s[n] = c[4];
        s4s[n] = c[5];
        if (md == 1)      { abD[n * 16] = 0.0;  abD[n * 16 + 1] = 0.0;  abc[n] = 0; }
        else if (md != 0) { abD[n * 16] = c[2]; abD[n * 16 + 1] = c[3]; abc[n] = neg; }
        else              { abD[n * 16] = 0.0;  abD[n * 16 + 1] = 0.0; }  // gather fills
        s_md = md; s_k = k;
    }
    __syncthreads();
    if (s_md != 0) return;
    // ---- count-histogram reduction (2 thread-groups × 50 slices)
    if (t < NBIN) lc[t] = 0;
    __syncthreads();
    {
        const int bin = t & (NBIN - 1);
        const int j0 = (t < NBIN) ? 0 : SBPS / 2;
        const int j1 = (t < NBIN) ? SBPS / 2 : SBPS;
        int c = 0;
        for (int j = j0; j < j1; ++j) c += ((const int*)(base + (size_t)j * SLW))[bin];
        atomicAdd(&lc[bin], c);
    }
    __syncthreads();
    if (t < 64) { int b, r; if (wave_find(lc, NBIN, s_k, &b, &r)) { sb1 = b; sk1 = r; } }
    __syncthreads();
    const int B = sb1;
    if (!t) { b1o[n] = sb1; k1o[n] = sk1; }
    int ac = (t < NBIN && t > B) ? lc[t] : 0;
    for (int off = 32; off; off >>= 1) ac += __shfl_down(ac, off, 64);
    if (!lane) ric[wid] = ac;
    __syncthreads();
    if (!t) abc[n] = ric[0] + ric[1] + ric[2] + ric[3];
}

// ---------------- mode-0 gather: above-bin value sums + boundary candidates -
__global__ void k_gather(const float* __restrict__ outputs, const float* __restrict__ labels,
                         const float* __restrict__ tmask,
                         const int* __restrict__ mode, const int* __restrict__ b1a,
                         int* __restrict__ cand_cnt, unsigned* __restrict__ ck,
                         float* __restrict__ cv1, float* __restrict__ cv2,
                         double* __restrict__ abD) {
    const int n = blockIdx.y;
    if (mode[n] != 0) return;   // modes 1/2/3 fully resolved in sel1
    const int b1n = b1a[n];
    __shared__ int lcnt, lbase;
    __shared__ unsigned lsk[BCAP];
    __shared__ float lv1[BCAP], lv2[BCAP];
    __shared__ double rdd[4][2];
    const int t = threadIdx.x, lane = t & 63, wid = t >> 6;
    if (!t) lcnt = 0;
    __syncthreads();
    const float* bp = outputs + (size_t)n * 2 * HWSZ;
    const float4* P  = (const float4*)bp;
    const float4* Th = P + NF4;
    const float4* G  = (const float4*)(labels + (size_t)n * 2 * HWSZ);
    const float4* T  = (const float4*)(tmask + (size_t)n * HWSZ);
    const int stride = GBPS * 256;
    float a1 = 0.f, a2 = 0.f;
    for (int i4 = blockIdx.x * 256 + t; i4 < NF4; i4 += stride) {
        float4 p = P[i4], th = Th[i4], g = G[i4], m = T[i4];
        const float* pp = (const float*)&p;  const float* tt = (const float*)&th;
        const float* gg = (const float*)&g;  const float* mm = (const float*)&m;
#pragma unroll
        for (int e = 0; e < 4; ++e) {
            bool neg = (gg[e] <= 0.5f) && (mm[e] > 0.5f);
            int bin = pbin(pp[e]);
            if (neg && bin >= b1n) {
                float o1, o2; bce_pair(pp[e], tt[e], false, o1, o2);
                if (bin > b1n) { a1 += o1; a2 += o2; }
                else {
                    int idx = atomicAdd(&lcnt, 1);
                    if (idx < BCAP) { lsk[idx] = fkey(pp[e]); lv1[idx] = o1; lv2[idx] = o2; }
                    else {
                        int gi = atomicAdd(&cand_cnt[n * PADI], 1);   // rare overflow
                        if (gi < CAP) { ck[n * CAP + gi] = fkey(pp[e]); cv1[n * CAP + gi] = o1; cv2[n * CAP + gi] = o2; }
                    }
                }
            }
        }
    }
    double v0 = a1, v1 = a2;
    for (int off = 32; off; off >>= 1) {
        v0 += __shfl_down(v0, off, 64);
        v1 += __shfl_down(v1, off, 64);
    }
    if (!lane) { rdd[wid][0] = v0; rdd[wid][1] = v1; }
    __syncthreads();
    if (!t) {
        double sA = rdd[0][0] + rdd[1][0] + rdd[2][0] + rdd[3][0];
        double sB = rdd[0][1] + rdd[1][1] + rdd[2][1] + rdd[3][1];
        if (sA != 0.0) atomicAdd(&abD[n * 16], sA);
        if (sB != 0.0) atomicAdd(&abD[n * 16 + 1], sB);
    }
    __syncthreads();
    const int cnt = min(lcnt, BCAP);
    if (!t && cnt) lbase = atomicAdd(&cand_cnt[n * PADI], cnt);
    __syncthreads();
    if (cnt) {
        const int bb = lbase;
        for (int i = t; i < cnt; i += 256) {
            int gi = bb + i;
            if (gi < CAP) { ck[n * CAP + gi] = lsk[i]; cv1[n * CAP + gi] = lv1[i]; cv2[n * CAP + gi] = lv2[i]; }
        }
    }
}

// ---------------- per-sample finalize + fused global reduction --------------
__global__ void k_final(const float* __restrict__ outputs, const float* __restrict__ labels,
                        const float* __restrict__ tmask,
                        const int* __restrict__ mode, const int* __restrict__ b1a,
                        const int* __restrict__ k1a, const int* __restrict__ poss,
                        const int* __restrict__ cand_cnt, const unsigned* __restrict__ ck,
                        const float* __restrict__ cv1, const float* __restrict__ cv2,
                        const double* __restrict__ psum, const double* __restrict__ abD,
                        const int* __restrict__ abc, double* __restrict__ res,
                        const double* __restrict__ s3s, const double* __restrict__ s4s,
                        unsigned* __restrict__ done, float* __restrict__ out) {
    __shared__ unsigned sk[CAP];
    __shared__ float sv1[CAP], sv2[CAP];
    __shared__ int h[2048];
    __shared__ int sbh, srh, sbm, srm, sbl;
    __shared__ double rd[4][2];
    __shared__ int ri[4];
    const int n = blockIdx.x, t = threadIdx.x;
    const int md = mode[n];
    double f1r = 0.0, f2r = 0.0; int fcr = 0;
    if (md == 0) {
        const int k1 = k1a[n];
        const int cc = cand_cnt[n * PADI];
        float f1 = 0.f, f2 = 0.f; int fc = 0;
        if (cc <= CAP) {
            for (int i = t; i < cc; i += 256) {
                sk[i] = ck[n * CAP + i]; sv1[i] = cv1[n * CAP + i]; sv2[i] = cv2[n * CAP + i];
            }
            for (int i = t; i < 2048; i += 256) h[i] = 0;
            __syncthreads();
            for (int i = t; i < cc; i += 256) atomicAdd(&h[sk[i] >> 21], 1);
            __syncthreads();
            if (t < 64) { int b, r; if (wave_find(h, 2048, k1, &b, &r)) { sbh = b; srh = r; } }
            __syncthreads();
            const unsigned bh = (unsigned)sbh; const int r2 = srh;
            for (int i = t; i < 2048; i += 256) h[i] = 0;
            __syncthreads();
            for (int i = t; i < cc; i += 256)
                if ((sk[i] >> 21) == bh) atomicAdd(&h[(sk[i] >> 10) & 0x7FFu], 1);
            __syncthreads();
            if (t < 64) { int b, r; if (wave_find(h, 2048, r2, &b, &r)) { sbm = b; srm = r; } }
            __syncthreads();
            const unsigned bm = (unsigned)sbm; const int r3 = srm;
            for (int i = t; i < 1024; i += 256) h[i] = 0;
            __syncthreads();
            for (int i = t; i < cc; i += 256)
                if ((sk[i] >> 10) == ((bh << 11) | bm)) atomicAdd(&h[sk[i] & 0x3FFu], 1);
            __syncthreads();
            if (t < 64) { int b, r; if (wave_find(h, 1024, r3, &b, &r)) sbl = b; }
            __syncthreads();
            const unsigned thr_key = (bh << 21) | (bm << 10) | (unsigned)sbl;
            for (int i = t; i < cc; i += 256)
                if (sk[i] >= thr_key) { f1 += sv1[i]; f2 += sv2[i]; fc++; }
        } else {
            // slow path: rescan boundary bin from global (general insurance)
            const int b1n = b1a[n];
            const float* Pp = outputs + (size_t)n * 2 * HWSZ;
            const float* Thp = Pp + HWSZ;
            const float* Gp = labels + (size_t)n * 2 * HWSZ;
            const float* Tp = tmask + (size_t)n * HWSZ;
            for (int i = t; i < 2048; i += 256) h[i] = 0;
            __syncthreads();
            for (int i = t; i < HWSZ; i += 256) {
                float pv = Pp[i];
                if (Gp[i] <= 0.5f && Tp[i] > 0.5f && pbin(pv) == b1n)
                    atomicAdd(&h[fkey(pv) >> 21], 1);
            }
            __syncthreads();
            if (t < 64) { int b, r; if (wave_find(h, 2048, k1, &b, &r)) { sbh = b; srh = r; } }
            __syncthreads();
            const unsigned bh = (unsigned)sbh; const int r2 = srh;
            for (int i = t; i < 2048; i += 256) h[i] = 0;
            __syncthreads();
            for (int i = t; i < HWSZ; i += 256) {
                float pv = Pp[i]; unsigned key = fkey(pv);
                if (Gp[i] <= 0.5f && Tp[i] > 0.5f && pbin(pv) == b1n && (key >> 21) == bh)
                    atomicAdd(&h[(key >> 10) & 0x7FFu], 1);
            }
            __syncthreads();
            if (t < 64) { int b, r; if (wave_find(h, 2048, r2, &b, &r)) { sbm = b; srm = r; } }
            __syncthreads();
            const unsigned bm = (unsigned)sbm; const int r3 = srm;
            for (int i = t; i < 1024; i += 256) h[i] = 0;
            __syncthreads();
            for (int i = t; i < HWSZ; i += 256) {
                float pv = Pp[i]; unsigned key = fkey(pv);
                if (Gp[i] <= 0.5f && Tp[i] > 0.5f && pbin(pv) == b1n && (key >> 10) == ((bh << 11) | bm))
                    atomicAdd(&h[key & 0x3FFu], 1);
            }
            __syncthreads();
            if (t < 64) { int b, r; if (wave_find(h, 1024, r3, &b, &r)) sbl = b; }
            __syncthreads();
            const unsigned thr_key = (bh << 21) | (bm << 10) | (unsigned)sbl;
            for (int i = t; i < HWSZ; i += 256) {
                float pv = Pp[i];
                if (Gp[i] <= 0.5f && Tp[i] > 0.5f && pbin(pv) == b1n && fkey(pv) >= thr_key) {
                    float b1v, b2v; bce_pair(pv, Thp[i], false, b1v, b2v);
                    f1 += b1v; f2 += b2v; fc++;
                }
            }
        }
        double v0 = f1, v1 = f2;
        for (int off = 32; off; off >>= 1) {
            v0 += __shfl_down(v0, off, 64);
            v1 += __shfl_down(v1, off, 64);
            fc += __shfl_down(fc, off, 64);
        }
        const int lane = t & 63, wid = t >> 6;
        if (!lane) { rd[wid][0] = v0; rd[wid][1] = v1; ri[wid] = fc; }
        __syncthreads();
        if (!t) {
            f1r = rd[0][0] + rd[1][0] + rd[2][0] + rd[3][0];
            f2r = rd[0][1] + rd[1][1] + rd[2][1] + rd[3][1];
            fcr = ri[0] + ri[1] + ri[2] + ri[3];
        }
    }
    if (!t) {
        res[n * 3 + 0] = psum[n * 2 + 0] + abD[n * 16] + f1r;
        res[n * 3 + 1] = psum[n * 2 + 1] + abD[n * 16 + 1] + f2r;
        res[n * 3 + 2] = (double)poss[n] + (double)abc[n] + (double)fcr;
        __threadfence();                                   // publish res before signaling
        unsigned v = atomicAdd(done, 1u);
        if (v == NS - 1) {                                 // last block: fused k_fin
            __threadfence();                               // acquire all res stores
            double A = 0.0, Bb = 0.0, C = 0.0, S3 = 0.0, S4 = 0.0;
            for (int m = 0; m < NS; ++m) {
                A += res[m * 3 + 0]; Bb += res[m * 3 + 1]; C += res[m * 3 + 2];
                S3 += s3s[m]; S4 += s4s[m];
            }
            double lp = (C > 0.0) ? A / C : 0.0;
            double lb = (C > 0.0) ? Bb / C : 0.0;
            double lt = S3 / (S4 + 1e-6);
            out[0] = (float)(lp + lb + 10.0 * lt);
            out[1] = (float)lp;
            out[2] = (float)lb;
            out[3] = (float)lt;
        }
    }
}

extern "C" void kernel_launch(void* const* d_in, const int* in_sizes, int n_in,
                              void* d_out, int out_size, void* d_ws, size_t ws_size,
                              hipStream_t stream) {
    const float* outputs = (const float*)d_in[0];
    const float* labels  = (const float*)d_in[1];
    const float* tmask   = (const float*)d_in[2];
    const float* gd      = (const float*)d_in[3];
    float* out = (float*)d_out;

    char* ws = (char*)d_ws;
    double* s3s   = (double*)ws;                 // NS
    double* s4s   = s3s + NS;                    // NS
    double* psum  = s4s + NS;                    // NS*2
    double* abD   = psum + NS * 2;               // NS*16 (padded: [n*16]=ab1,[n*16+1]=ab2)
    double* res   = abD + NS * 16;               // NS*3
    int* abc      = (int*)(res + NS * 3);        // NS
    int* mode     = abc + NS;                    // NS
    int* b1       = mode + NS;                   // NS
    int* k1       = b1 + NS;                     // NS
    int* poss     = k1 + NS;                     // NS
    unsigned* done = (unsigned*)(poss + NS);     // 1 (+pad to 8)
    int* cand_cnt = (int*)(done + 8);            // NS*PADI (padded counters)
    float* part   = (float*)(cand_cnt + NS * PADI);  // NS*SBPS*SLW (fully written)
    unsigned* ck  = (unsigned*)(part + (size_t)NS * SBPS * SLW);  // NS*CAP
    float* cv1    = (float*)(ck + NS * CAP);
    float* cv2    = cv1 + NS * CAP;
    (void)cv2; (void)ws_size; (void)in_sizes; (void)n_in; (void)out_size;

    // NOTE: no memset needed — k_sel1 zeroes cand_cnt and done each call,
    // and every other workspace word is written before it is read.
    k_scan1<<<dim3(SBPS, NS), 256, 0, stream>>>(outputs, labels, tmask, gd, part);
    k_sel1<<<NS, 256, 0, stream>>>(part, mode, b1, k1, poss, psum, abD, abc, s3s, s4s,
                                   cand_cnt, done);
    k_gather<<<dim3(GBPS, NS), 256, 0, stream>>>(outputs, labels, tmask, mode, b1,
                                                 cand_cnt, ck, cv1, cv2, abD);
    k_final<<<NS, 256, 0, stream>>>(outputs, labels, tmask, mode, b1, k1, poss, cand_cnt,
                                    ck, cv1, cv2, psum, abD, abc, res, s3s, s4s, done, out);
}